// Round 1
// baseline (104.168 us; speedup 1.0000x reference)
//
#include <hip/hip_runtime.h>
#include <math.h>

#define ALPHA 0.2f

// Problem constants (fixed by reference)
#define NB 4
#define TT 24
#define VV 32
#define HW 256   // 16*16

// ws layout (float offsets)
#define WS_WH    0              // [N][T][P][V] = 4*24*256*32 = 786432
#define WS_EPART 786432         // [128 blocks][2][32][24]   = 196608
#define WS_ATT   983040         // [N][T][i*32+j]            = 98304
#define WS_ADJN  1081344        // [i][v]                    = 1024

// ---------------------------------------------------------------------------
// Kernel 1: per (n, p-tile of 8): Wh[n][t][p][v] -> ws, plus Ei/Ej partials.
// ---------------------------------------------------------------------------
__global__ __launch_bounds__(256) void k1_wh_e(
    const float* __restrict__ h, const float* __restrict__ Wp,
    const float* __restrict__ ap, float* __restrict__ ws)
{
  __shared__ float WL[576];   // W[t'][t]
  __shared__ float aL[512];
  __shared__ float EiL[768];  // [v][tt]
  __shared__ float EjL[768];

  const int b   = blockIdx.x;
  const int n   = b >> 5;
  const int pt  = b & 31;
  const int p0  = pt * 8;
  const int tid = threadIdx.x;
  const int v   = tid & 31;
  const int g   = tid >> 5;       // 0..7 -> local p
  const int p   = p0 + g;

  for (int idx = tid; idx < 576; idx += 256) WL[idx] = Wp[idx];
  for (int idx = tid; idx < 512; idx += 256) aL[idx] = ap[idx];
  for (int idx = tid; idx < 768; idx += 256) { EiL[idx] = 0.f; EjL[idx] = 0.f; }

  // h[n,p,t',v] : 24 coalesced dword loads per thread (lanes sweep v)
  float hrow[24];
  const float* hp = h + (size_t)(n * HW + p) * TT * VV + v;
  #pragma unroll
  for (int t2 = 0; t2 < 24; ++t2) hrow[t2] = hp[t2 * 32];

  __syncthreads();

  // Wh[p][t][v] for all t, accumulated in registers
  float acc[24];
  #pragma unroll
  for (int t = 0; t < 24; ++t) acc[t] = 0.f;
  #pragma unroll
  for (int t2 = 0; t2 < 24; ++t2) {
    const float hv = hrow[t2];
    const float4* wrow = (const float4*)&WL[t2 * 24];   // 96B-aligned
    #pragma unroll
    for (int q = 0; q < 6; ++q) {
      float4 w4 = wrow[q];
      acc[q*4+0] += hv * w4.x; acc[q*4+1] += hv * w4.y;
      acc[q*4+2] += hv * w4.z; acc[q*4+3] += hv * w4.w;
    }
  }

  // scrambled-view q mapping: q_i = 768*hh + 24*w + t ; q_j = q_i + 384
  const int hh = p >> 4, w = p & 15;
  const int qi0 = hh * 768 + w * 24;
  const int qj0 = qi0 + 384;
  const int tti0 = qi0 >> 9;
  const int ttj0 = qj0 >> 9;
  const bool cri = (((qi0 + 23) >> 9) != tti0);
  const bool crj = (((qj0 + 23) >> 9) != ttj0);

  float ai0 = 0.f, ai1 = 0.f, aj0 = 0.f, aj1 = 0.f;

  float* whout = ws + WS_WH + (size_t)n * TT * HW * VV + (size_t)p * VV + v;
  #pragma unroll
  for (int t = 0; t < 24; ++t) {
    const float wh = acc[t];
    whout[(size_t)t * HW * VV] = wh;          // [n][t][p][v], coalesced 128B
    const int qi = qi0 + t;
    const float ci = aL[qi & 511] * wh;
    const bool si = ((qi >> 9) != tti0);
    ai0 += si ? 0.f : ci;  ai1 += si ? ci : 0.f;
    const int qj = qj0 + t;
    const float cj = aL[qj & 511] * wh;
    const bool sj = ((qj >> 9) != ttj0);
    aj0 += sj ? 0.f : cj;  aj1 += sj ? cj : 0.f;
  }

  atomicAdd(&EiL[v * 24 + tti0], ai0);
  if (cri) atomicAdd(&EiL[v * 24 + tti0 + 1], ai1);
  atomicAdd(&EjL[v * 24 + ttj0], aj0);
  if (crj) atomicAdd(&EjL[v * 24 + ttj0 + 1], aj1);
  __syncthreads();

  float* ep = ws + WS_EPART + (size_t)b * 1536;
  for (int idx = tid; idx < 768; idx += 256) {
    ep[idx]       = EiL[idx];
    ep[768 + idx] = EjL[idx];
  }
}

// ---------------------------------------------------------------------------
// Kernel 2: per n: reduce E partials, softmax att[n][t][i*32+j] -> ws.
//           Block 0 additionally computes adj_norm from B_param -> ws.
// ---------------------------------------------------------------------------
__global__ __launch_bounds__(256) void k2_att(
    const float* __restrict__ Bp, float* __restrict__ ws)
{
  __shared__ float E[2 * 32 * 25];    // Ei at [v*25+t], Ej at 800 + [v*25+t]
  __shared__ float adjw[1024];
  __shared__ float dinvL[32];
  __shared__ float redmn[4], redmx[4];
  __shared__ float smn, smx;

  const int n = blockIdx.x;
  const int tid = threadIdx.x;

  // reduce 32 per-tile partials
  const float* ep = ws + WS_EPART + (size_t)n * 32 * 1536;
  for (int o = tid; o < 1536; o += 256) {
    float s = 0.f;
    #pragma unroll 4
    for (int k = 0; k < 32; ++k) s += ep[(size_t)k * 1536 + o];
    const int side = o >> 9 >= 1 ? (o >= 768 ? 1 : 0) : 0;  // side = o/768
    const int rem = o - (o >= 768 ? 768 : 0);
    const int vv = rem / 24, t = rem - vv * 24;
    E[(o >= 768 ? 800 : 0) + vv * 25 + t] = s;
    (void)side;
  }

  // adj_norm (block 0 only; barriers are block-uniform)
  float lmn = 1e30f, lmx = -1e30f;
  if (n == 0) {
    for (int o = tid; o < 1024; o += 256) {
      const int i = o >> 5, j = o & 31;
      const float x = Bp[o] + 1e-6f + (i == j ? 1.f : 0.f);
      adjw[o] = x;
      lmn = fminf(lmn, x); lmx = fmaxf(lmx, x);
    }
    #pragma unroll
    for (int off = 32; off > 0; off >>= 1) {
      lmn = fminf(lmn, __shfl_down(lmn, off));
      lmx = fmaxf(lmx, __shfl_down(lmx, off));
    }
    if ((tid & 63) == 0) { redmn[tid >> 6] = lmn; redmx[tid >> 6] = lmx; }
  }
  __syncthreads();
  if (n == 0 && tid == 0) {
    smn = fminf(fminf(redmn[0], redmn[1]), fminf(redmn[2], redmn[3]));
    smx = fmaxf(fmaxf(redmx[0], redmx[1]), fmaxf(redmx[2], redmx[3]));
  }
  __syncthreads();
  if (n == 0) {
    const float rs = 1.f / (smx - smn);
    for (int o = tid; o < 1024; o += 256) adjw[o] = (adjw[o] - smn) * rs;
  }
  __syncthreads();
  if (n == 0 && tid < 32) {
    float s = 0.f;
    #pragma unroll
    for (int j = 0; j < 32; ++j) s += adjw[tid * 32 + j];
    dinvL[tid] = rsqrtf(s);
  }
  __syncthreads();
  if (n == 0) {
    for (int o = tid; o < 1024; o += 256) {
      const int i = o >> 5, j = o & 31;
      ws[WS_ADJN + o] = adjw[o] * dinvL[i] * dinvL[j];
    }
  }

  // attention softmax over T per (i,j)
  for (int pair = tid; pair < 1024; pair += 256) {
    const int i = pair >> 5, j = pair & 31;
    const float* Ei = &E[i * 25];
    const float* Ej = &E[800 + j * 25];
    float ev[24];
    float mx = -1e30f;
    #pragma unroll
    for (int t = 0; t < 24; ++t) {
      float x = Ei[t] + Ej[t];
      x = x > 0.f ? x : ALPHA * x;          // LeakyReLU
      ev[t] = x; mx = fmaxf(mx, x);
    }
    float s = 0.f;
    #pragma unroll
    for (int t = 0; t < 24; ++t) { const float e = __expf(ev[t] - mx); ev[t] = e; s += e; }
    const float r = 1.f / s;
    float* attout = ws + WS_ATT + (size_t)n * TT * 1024 + pair;
    #pragma unroll
    for (int t = 0; t < 24; ++t) attout[(size_t)t * 1024] = ev[t] * r;
  }
}

// ---------------------------------------------------------------------------
// Kernel 3: per (n,t): M[v,j] = adjn^T @ att_t ; out[p,v] = sig(elu(Wh_t @ M^T))
// ---------------------------------------------------------------------------
__global__ __launch_bounds__(256) void k3_out(
    float* __restrict__ out, const float* __restrict__ ws)
{
  __shared__ float attL[1024];   // [i*32+j]
  __shared__ float adjnL[1024];  // [i*32+v]
  __shared__ float MT[1024];     // [j*32+v]
  __shared__ float WhL[8192];    // [p*32+j]

  const int b = blockIdx.x;
  const int n = b / 24, t = b - n * 24;
  const int tid = threadIdx.x;

  const float* attg = ws + WS_ATT + (size_t)(n * 24 + t) * 1024;
  for (int o = tid; o < 1024; o += 256) {
    attL[o]  = attg[o];
    adjnL[o] = ws[WS_ADJN + o];
  }
  const float4* wh4 = (const float4*)(ws + WS_WH + (size_t)(n * 24 + t) * 8192);
  float4* whl4 = (float4*)WhL;
  for (int o = tid; o < 2048; o += 256) whl4[o] = wh4[o];
  __syncthreads();

  for (int o = tid; o < 1024; o += 256) {
    const int j = o >> 5, v = o & 31;
    float s = 0.f;
    #pragma unroll
    for (int i = 0; i < 32; ++i) s += adjnL[i * 32 + v] * attL[i * 32 + j];
    MT[o] = s;
  }
  __syncthreads();

  const int v = tid & 31, g = tid >> 5;
  // hoist M column for this v into registers (32 conflict-free b32 reads)
  float mv[32];
  #pragma unroll
  for (int jj = 0; jj < 32; ++jj) mv[jj] = MT[jj * 32 + v];

  float* outg = out + (size_t)n * HW * TT * VV + (size_t)t * VV + v;
  #pragma unroll 4
  for (int k = 0; k < 32; ++k) {
    const int p = (g << 5) + k;
    const float4* wr = (const float4*)&WhL[p * 32];   // broadcast b128 reads
    float accv = 0.f;
    #pragma unroll
    for (int q = 0; q < 8; ++q) {
      float4 w4 = wr[q];
      accv += w4.x * mv[q*4+0] + w4.y * mv[q*4+1] + w4.z * mv[q*4+2] + w4.w * mv[q*4+3];
    }
    const float e  = accv > 0.f ? accv : (__expf(accv) - 1.f);  // ELU(alpha=1)
    const float sg = 1.f / (1.f + __expf(-e));                  // sigmoid
    outg[(size_t)p * TT * VV] = sg;
  }
}

// ---------------------------------------------------------------------------
extern "C" void kernel_launch(void* const* d_in, const int* in_sizes, int n_in,
                              void* d_out, int out_size, void* d_ws, size_t ws_size,
                              hipStream_t stream) {
  const float* h  = (const float*)d_in[0];   // (4,16,16,24,32) f32
  const float* Wp = (const float*)d_in[1];   // (24,24)
  const float* ap = (const float*)d_in[2];   // (512,1)
  const float* Bp = (const float*)d_in[3];   // (32,32)
  float* out = (float*)d_out;                // (4,16,16,24,32) f32
  float* ws  = (float*)d_ws;

  hipLaunchKernelGGL(k1_wh_e, dim3(NB * 32), dim3(256), 0, stream, h, Wp, ap, ws);
  hipLaunchKernelGGL(k2_att,  dim3(NB),      dim3(256), 0, stream, Bp, ws);
  hipLaunchKernelGGL(k3_out,  dim3(NB * 24), dim3(256), 0, stream, out, ws);
}

// Round 2
// 98.552 us; speedup vs baseline: 1.0570x; 1.0570x over previous
//
#include <hip/hip_runtime.h>
#include <math.h>

#define ALPHA 0.2f

// Problem constants (fixed by reference)
#define NB 4
#define TT 24
#define VV 32
#define HW 256   // 16*16

// ws layout (float offsets)
#define WS_WH    0              // [N][T][P][V] = 4*24*256*32 = 786432
#define WS_EPART 786432         // [N][32 tiles][2][32][24]  = 196608

// ---------------------------------------------------------------------------
// Kernel 1: per (n, p-tile of 8): Wh[n][t][p][v] -> ws, plus Ei/Ej partials.
// ---------------------------------------------------------------------------
__global__ __launch_bounds__(256) void k1_wh_e(
    const float* __restrict__ h, const float* __restrict__ Wp,
    const float* __restrict__ ap, float* __restrict__ ws)
{
  __shared__ float WL[576];   // W[t'][t]
  __shared__ float aL[512];
  __shared__ float EiL[768];  // [v][tt]
  __shared__ float EjL[768];

  const int b   = blockIdx.x;
  const int n   = b >> 5;
  const int pt  = b & 31;
  const int p0  = pt * 8;
  const int tid = threadIdx.x;
  const int v   = tid & 31;
  const int g   = tid >> 5;       // 0..7 -> local p
  const int p   = p0 + g;

  for (int idx = tid; idx < 576; idx += 256) WL[idx] = Wp[idx];
  for (int idx = tid; idx < 512; idx += 256) aL[idx] = ap[idx];
  for (int idx = tid; idx < 768; idx += 256) { EiL[idx] = 0.f; EjL[idx] = 0.f; }

  // h[n,p,t',v] : 24 coalesced dword loads per thread (lanes sweep v)
  float hrow[24];
  const float* hp = h + (size_t)(n * HW + p) * TT * VV + v;
  #pragma unroll
  for (int t2 = 0; t2 < 24; ++t2) hrow[t2] = hp[t2 * 32];

  __syncthreads();

  // Wh[p][t][v] for all t, accumulated in registers
  float acc[24];
  #pragma unroll
  for (int t = 0; t < 24; ++t) acc[t] = 0.f;
  #pragma unroll
  for (int t2 = 0; t2 < 24; ++t2) {
    const float hv = hrow[t2];
    const float4* wrow = (const float4*)&WL[t2 * 24];   // 96B-aligned
    #pragma unroll
    for (int q = 0; q < 6; ++q) {
      float4 w4 = wrow[q];
      acc[q*4+0] += hv * w4.x; acc[q*4+1] += hv * w4.y;
      acc[q*4+2] += hv * w4.z; acc[q*4+3] += hv * w4.w;
    }
  }

  // scrambled-view q mapping: q_i = 768*hh + 24*w + t ; q_j = q_i + 384
  const int hh = p >> 4, w = p & 15;
  const int qi0 = hh * 768 + w * 24;
  const int qj0 = qi0 + 384;
  const int tti0 = qi0 >> 9;
  const int ttj0 = qj0 >> 9;
  const bool cri = (((qi0 + 23) >> 9) != tti0);
  const bool crj = (((qj0 + 23) >> 9) != ttj0);

  float ai0 = 0.f, ai1 = 0.f, aj0 = 0.f, aj1 = 0.f;

  float* whout = ws + WS_WH + (size_t)n * TT * HW * VV + (size_t)p * VV + v;
  #pragma unroll
  for (int t = 0; t < 24; ++t) {
    const float wh = acc[t];
    whout[(size_t)t * HW * VV] = wh;          // [n][t][p][v], coalesced 128B
    const int qi = qi0 + t;
    const float ci = aL[qi & 511] * wh;
    const bool si = ((qi >> 9) != tti0);
    ai0 += si ? 0.f : ci;  ai1 += si ? ci : 0.f;
    const int qj = qj0 + t;
    const float cj = aL[qj & 511] * wh;
    const bool sj = ((qj >> 9) != ttj0);
    aj0 += sj ? 0.f : cj;  aj1 += sj ? cj : 0.f;
  }

  atomicAdd(&EiL[v * 24 + tti0], ai0);
  if (cri) atomicAdd(&EiL[v * 24 + tti0 + 1], ai1);
  atomicAdd(&EjL[v * 24 + ttj0], aj0);
  if (crj) atomicAdd(&EjL[v * 24 + ttj0 + 1], aj1);
  __syncthreads();

  // [n][tile k][o in 0..1536) — coalesced write; k2 reads coalesced over o.
  float* ep = ws + WS_EPART + (size_t)b * 1536;
  for (int idx = tid; idx < 768; idx += 256) {
    ep[idx]       = EiL[idx];
    ep[768 + idx] = EjL[idx];
  }
}

// ---------------------------------------------------------------------------
// Kernel 2 (fused): per (n,t) block:
//   E = reduce(EPART[n]) ; adjn = norm(B) (redundant per block) ;
//   att_t[i,j] = softmax_t(LReLU(Ei+Ej)) ; MT[j,v] = sum_i adjn[i,v] att[i,j] ;
//   out[p,t,v] = sigmoid(elu(sum_j Wh[t,p,j] * MT[j,v]))
// ---------------------------------------------------------------------------
__global__ __launch_bounds__(256) void k2_fused(
    const float* __restrict__ Bp, float* __restrict__ out,
    const float* __restrict__ ws)
{
  __shared__ float E[1600];      // Ei at [v*25+t], Ej at 800 + [v*25+t]
  __shared__ float adjw[1024];   // becomes adj_norm in place
  __shared__ float attL[1024];   // att for this block's t: [i*32+j]
  __shared__ float MT[1024];     // [j*32+v]
  __shared__ float WhL[8192];    // [p*32+v]
  __shared__ float dinvL[32];
  __shared__ float redmn[4], redmx[4];
  __shared__ float smn, smx;

  const int b = blockIdx.x;
  const int n = b / 24, t = b - n * 24;
  const int tid = threadIdx.x;

  // --- stage Wh tile (independent of everything until the last phase) ---
  const float4* wh4 = (const float4*)(ws + WS_WH + (size_t)(n * 24 + t) * 8192);
  float4* whl4 = (float4*)WhL;
  for (int o = tid; o < 2048; o += 256) whl4[o] = wh4[o];

  // --- reduce E partials over the 32 p-tiles (coalesced over lanes) ---
  const float* ep = ws + WS_EPART + (size_t)n * 32 * 1536;
  for (int o = tid; o < 1536; o += 256) {
    float s = 0.f;
    #pragma unroll 8
    for (int k = 0; k < 32; ++k) s += ep[(size_t)k * 1536 + o];
    const int side = (o >= 768) ? 1 : 0;
    const int rem = o - side * 768;
    const int vv = rem / 24, tt = rem - vv * 24;
    E[side * 800 + vv * 25 + tt] = s;
  }

  // --- adjacency load + block min/max (register phase) ---
  float lmn = 1e30f, lmx = -1e30f;
  for (int o = tid; o < 1024; o += 256) {
    const int i = o >> 5, j = o & 31;
    const float x = Bp[o] + 1e-6f + (i == j ? 1.f : 0.f);
    adjw[o] = x;
    lmn = fminf(lmn, x); lmx = fmaxf(lmx, x);
  }
  #pragma unroll
  for (int off = 32; off > 0; off >>= 1) {
    lmn = fminf(lmn, __shfl_down(lmn, off));
    lmx = fmaxf(lmx, __shfl_down(lmx, off));
  }
  if ((tid & 63) == 0) { redmn[tid >> 6] = lmn; redmx[tid >> 6] = lmx; }
  __syncthreads();

  if (tid == 0) {
    smn = fminf(fminf(redmn[0], redmn[1]), fminf(redmn[2], redmn[3]));
    smx = fmaxf(fmaxf(redmx[0], redmx[1]), fmaxf(redmx[2], redmx[3]));
  }
  __syncthreads();

  const float rs = 1.f / (smx - smn);
  for (int o = tid; o < 1024; o += 256) adjw[o] = (adjw[o] - smn) * rs;
  __syncthreads();

  if (tid < 32) {
    float s = 0.f;
    #pragma unroll
    for (int j = 0; j < 32; ++j) s += adjw[tid * 32 + j];
    dinvL[tid] = rsqrtf(s);
  }
  __syncthreads();

  // finalize adj_norm in place; compute this t's att slice in the same phase
  for (int o = tid; o < 1024; o += 256) {
    const int i = o >> 5, j = o & 31;
    adjw[o] = adjw[o] * dinvL[i] * dinvL[j];
  }
  for (int pair = tid; pair < 1024; pair += 256) {
    const int i = pair >> 5, j = pair & 31;
    const float* Ei = &E[i * 25];
    const float* Ej = &E[800 + j * 25];
    float ev[24];
    float mx = -1e30f;
    #pragma unroll
    for (int t2 = 0; t2 < 24; ++t2) {
      float x = Ei[t2] + Ej[t2];
      x = x > 0.f ? x : ALPHA * x;          // LeakyReLU
      ev[t2] = x; mx = fmaxf(mx, x);
    }
    float s = 0.f;
    #pragma unroll
    for (int t2 = 0; t2 < 24; ++t2) { const float e = __expf(ev[t2] - mx); ev[t2] = e; s += e; }
    attL[pair] = ev[t] / s;
  }
  __syncthreads();

  // MT[j,v] = sum_i adjn[i,v] * att[i,j]
  for (int o = tid; o < 1024; o += 256) {
    const int j = o >> 5, v = o & 31;
    float s = 0.f;
    #pragma unroll
    for (int i = 0; i < 32; ++i) s += adjw[i * 32 + v] * attL[i * 32 + j];
    MT[o] = s;
  }
  __syncthreads();

  // out[p, t, v] = sigmoid(elu( sum_j WhL[p,j] * MT[j,v] ))
  const int v = tid & 31, g = tid >> 5;
  float mv[32];
  #pragma unroll
  for (int jj = 0; jj < 32; ++jj) mv[jj] = MT[jj * 32 + v];

  float* outg = out + (size_t)n * HW * TT * VV + (size_t)t * VV + v;
  #pragma unroll 4
  for (int k = 0; k < 32; ++k) {
    const int p = (g << 5) + k;
    const float4* wr = (const float4*)&WhL[p * 32];   // broadcast b128 reads
    float accv = 0.f;
    #pragma unroll
    for (int q = 0; q < 8; ++q) {
      float4 w4 = wr[q];
      accv += w4.x * mv[q*4+0] + w4.y * mv[q*4+1] + w4.z * mv[q*4+2] + w4.w * mv[q*4+3];
    }
    const float e  = accv > 0.f ? accv : (__expf(accv) - 1.f);  // ELU(alpha=1)
    const float sg = 1.f / (1.f + __expf(-e));                  // sigmoid
    outg[(size_t)p * TT * VV] = sg;
  }
}

// ---------------------------------------------------------------------------
extern "C" void kernel_launch(void* const* d_in, const int* in_sizes, int n_in,
                              void* d_out, int out_size, void* d_ws, size_t ws_size,
                              hipStream_t stream) {
  const float* h  = (const float*)d_in[0];   // (4,16,16,24,32) f32
  const float* Wp = (const float*)d_in[1];   // (24,24)
  const float* ap = (const float*)d_in[2];   // (512,1)
  const float* Bp = (const float*)d_in[3];   // (32,32)
  float* out = (float*)d_out;                // (4,16,16,24,32) f32
  float* ws  = (float*)d_ws;

  hipLaunchKernelGGL(k1_wh_e,  dim3(NB * 32), dim3(256), 0, stream, h, Wp, ap, ws);
  hipLaunchKernelGGL(k2_fused, dim3(NB * 24), dim3(256), 0, stream, Bp, out, ws);
}